// Round 13
// baseline (652.652 us; speedup 1.0000x reference)
//
#include <hip/hip_runtime.h>
#include <hip/hip_fp16.h>
#include <math.h>

// GCN 2-layer (DGL GraphConv norm='both') as ONE persistent kernel, v2.
// Round-12 post-mortem fixes:
//  - occupancy 24%->~50%: NBLK=1024, __launch_bounds__(256,4) (4 blocks/CU;
//    LDS 24.6KB <= 40KB budget, compiler caps VGPR at 128)
//  - barrier spin throttled with s_sleep(8): r12's unthrottled 512 pollers on
//    8 device-scope lines contended the fabric (HBM 390GB/s, VALU 7%)
//  - P4/P5 merged (independent: src bins vs dst bins) -> 5 barriers, not 7
// Phases:
//  P1 edge bin-hist -> counts[bin][block] + raw featp=fp16(feat@W1)
//  P2 parallel exclusive scan of each bin's counts row (392 blocks)
//  P3 inline top-scan of rowSums -> bin bases; partition edges into 256-node
//     dst bins (packed src|dstLow<<17) + src-low bytes (ZERO global atomics)
//  P45 b<NB: per-dst-bin counting sort -> csr_src/row_start/in_deg
//      NB<=b<2NB: src-bin hist -> out_norm; scale featp rows by out_norm
//  P6 agg1: wave/node, 8 edge-groups x 8 fp16 chunks, unroll-2, register acc
//  P7 agg2: 16 lanes/node + sigmoid -> out
// Requires N <= 65536 (NB<=256, src in 17 bits). N=50000, E=800000.

#define BS   256
#define NBLK 1024
#define NBAR 8

__device__ __forceinline__ void gbar(int* bar, int phase) {
    __syncthreads();
    if (threadIdx.x == 0) {
        __threadfence();   // release: make this block's stores device-visible
        __hip_atomic_fetch_add(&bar[(blockIdx.x & (NBAR - 1)) * 32], 1,
                               __ATOMIC_RELAXED, __HIP_MEMORY_SCOPE_AGENT);
        const int target = NBLK * phase;
        for (;;) {
            int sum = 0;
            #pragma unroll
            for (int i = 0; i < NBAR; i++)
                sum += __hip_atomic_load(&bar[i * 32], __ATOMIC_RELAXED,
                                         __HIP_MEMORY_SCOPE_AGENT);
            if (sum >= target) break;
            __builtin_amdgcn_s_sleep(8);   // ~512cyc poll period: no fabric spam
        }
        __threadfence();   // acquire: invalidate stale cached lines
    }
    __syncthreads();
}

__global__ __launch_bounds__(BS, 4) void gcn_persist(
    const float* __restrict__ feat, const float* __restrict__ W1,
    const float* __restrict__ b1, const float* __restrict__ W2,
    const float* __restrict__ b2, const int* __restrict__ src,
    const int* __restrict__ dst,
    int* bar, int* countsD, int* countsS, int* rowSumD, int* rowSumS,
    int* dstBinBase, int* srcBinBase, int* packed, unsigned char* srcPart,
    int* csr_src, int* in_deg, int* row_start, float* out_norm, float* s_buf,
    __half* featp, float* out, int N, int E, int NB)
{
    __shared__ float w[64 * 64];   // 16 KB
    __shared__ int hA[256];
    __shared__ int hB[256];
    __shared__ int sc[256];
    __shared__ int rbD[256];
    __shared__ int rbS[256];
    __shared__ int curD[256];
    __shared__ int curS[256];
    __shared__ float onorm[256];

    const int tid  = threadIdx.x;
    const int b    = blockIdx.x;
    const int wv   = tid >> 6;
    const int lane = tid & 63;
    const int EB   = (E + NBLK - 1) / NBLK;
    const int elo  = b * EB;
    const int ehi  = (elo + EB < E) ? elo + EB : E;

    // ---------------- P1: edge hist + raw featp = fp16(feat @ W1) ------------
    hA[tid] = 0; hB[tid] = 0;
    for (int i = tid; i < 64 * 16; i += BS)
        ((float4*)w)[i] = ((const float4*)W1)[i];
    __syncthreads();
    for (int e = elo + tid; e < ehi; e += BS) {
        atomicAdd(&hA[dst[e] >> 8], 1);     // LDS int atomics: native, fast
        atomicAdd(&hB[src[e] >> 8], 1);
    }
    __syncthreads();
    if (tid < NB) {
        countsD[(size_t)tid * NBLK + b] = hA[tid];
        countsS[(size_t)tid * NBLK + b] = hB[tid];
    }
    for (int row = b * 4 + wv; row < N; row += NBLK * 4) {
        const float4* fr = (const float4*)(feat + (size_t)row * 64);
        float acc = 0.0f;
        #pragma unroll
        for (int k4 = 0; k4 < 16; k4++) {
            float4 a = fr[k4];                          // wave-uniform broadcast
            acc += a.x * w[(4 * k4 + 0) * 64 + lane];   // stride-1: conflict-free
            acc += a.y * w[(4 * k4 + 1) * 64 + lane];
            acc += a.z * w[(4 * k4 + 2) * 64 + lane];
            acc += a.w * w[(4 * k4 + 3) * 64 + lane];
        }
        featp[(size_t)row * 64 + lane] = __float2half(acc);   // unnormalized
    }
    gbar(bar, 1);

    // ---------------- P2: exclusive-scan each counts row (len NBLK) ----------
    if (b < 2 * NB) {
        int* row = (b < NB) ? (countsD + (size_t)b * NBLK)
                            : (countsS + (size_t)(b - NB) * NBLK);
        int a[4]; int s4 = 0;
        #pragma unroll
        for (int i = 0; i < 4; i++) { a[i] = row[4 * tid + i]; s4 += a[i]; }
        sc[tid] = s4; __syncthreads();
        for (int off = 1; off < 256; off <<= 1) {
            int u = (tid >= off) ? sc[tid - off] : 0; __syncthreads();
            sc[tid] += u; __syncthreads();
        }
        int run = sc[tid] - s4;
        #pragma unroll
        for (int i = 0; i < 4; i++) { int c = a[i]; row[4 * tid + i] = run; run += c; }
        if (tid == 255) {
            if (b < NB) rowSumD[b] = sc[255];
            else        rowSumS[b - NB] = sc[255];
        }
    }
    gbar(bar, 2);

    // ---------------- P3: top-scan + partition (no global atomics) -----------
    {
        int vD = (tid < NB) ? rowSumD[tid] : 0;
        sc[tid] = vD; __syncthreads();
        for (int off = 1; off < 256; off <<= 1) {
            int u = (tid >= off) ? sc[tid - off] : 0; __syncthreads();
            sc[tid] += u; __syncthreads();
        }
        rbD[tid] = sc[tid] - vD;
        __syncthreads();
        int vS = (tid < NB) ? rowSumS[tid] : 0;
        sc[tid] = vS; __syncthreads();
        for (int off = 1; off < 256; off <<= 1) {
            int u = (tid >= off) ? sc[tid - off] : 0; __syncthreads();
            sc[tid] += u; __syncthreads();
        }
        rbS[tid] = sc[tid] - vS;
        __syncthreads();
        if (b == 0) {
            if (tid < NB) { dstBinBase[tid] = rbD[tid]; srcBinBase[tid] = rbS[tid]; }
            if (tid == NB) {
                dstBinBase[NB] = rbD[NB - 1] + rowSumD[NB - 1];
                srcBinBase[NB] = rbS[NB - 1] + rowSumS[NB - 1];
            }
        }
        if (tid < NB) {
            curD[tid] = rbD[tid] + countsD[(size_t)tid * NBLK + b];
            curS[tid] = rbS[tid] + countsS[(size_t)tid * NBLK + b];
        }
        __syncthreads();
        for (int e = elo + tid; e < ehi; e += BS) {
            int d = dst[e], s2 = src[e];
            int pos = atomicAdd(&curD[d >> 8], 1);            // LDS atomic only
            packed[pos] = s2 | ((d & 255) << 17);
            int pos2 = atomicAdd(&curS[s2 >> 8], 1);
            srcPart[pos2] = (unsigned char)(s2 & 255);
        }
    }
    gbar(bar, 3);

    // ------- P45: dst-bin counting sort (b<NB) | src-bin norm+scale (b<2NB) --
    if (b < NB) {
        int lo = dstBinBase[b], hi = dstBinBase[b + 1];
        hA[tid] = 0; __syncthreads();
        for (int i = lo + tid; i < hi; i += BS)
            atomicAdd(&hA[(packed[i] >> 17) & 255], 1);
        __syncthreads();
        int v = hA[tid];
        sc[tid] = v; __syncthreads();
        for (int off = 1; off < 256; off <<= 1) {
            int u = (tid >= off) ? sc[tid - off] : 0; __syncthreads();
            sc[tid] += u; __syncthreads();
        }
        int ex = sc[tid] - v;
        int n = b * 256 + tid;
        if (n < N) { in_deg[n] = v; row_start[n] = lo + ex; }
        curD[tid] = lo + ex;
        __syncthreads();
        for (int i = lo + tid; i < hi; i += BS) {
            int pv = packed[i];
            int pos = atomicAdd(&curD[(pv >> 17) & 255], 1);
            csr_src[pos] = pv & 0x1FFFF;
        }
    } else if (b < 2 * NB) {
        int sb = b - NB;
        int lo = srcBinBase[sb], hi = srcBinBase[sb + 1];
        hA[tid] = 0; __syncthreads();
        for (int i = lo + tid; i < hi; i += BS)
            atomicAdd(&hA[srcPart[i]], 1);
        __syncthreads();
        float on = rsqrtf(fmaxf((float)hA[tid], 1.0f));
        onorm[tid] = on;
        int n = sb * 256 + tid;
        if (n < N) out_norm[n] = on;
        __syncthreads();
        __half2* base2 = (__half2*)(featp + (size_t)sb * 256 * 64);
        int rows = N - sb * 256; if (rows > 256) rows = 256;
        int cap = rows * 32;                      // 32 half2 per row
        for (int idx = tid; idx < cap; idx += BS) {
            float s2 = onorm[idx >> 5];
            float2 f = __half22float2(base2[idx]);
            base2[idx] = __floats2half2_rn(f.x * s2, f.y * s2);
        }
    }
    gbar(bar, 4);

    // ---------------- P6: agg1 — wave/node, register acc, unroll-2 -----------
    {
        int g = lane >> 3, l = lane & 7;
        const uint4* fp4 = (const uint4*)featp;
        for (int n = b * 4 + wv; n < N; n += NBLK * 4) {
            int start = row_start[n];
            int deg = in_deg[n];
            float acc[8] = {0, 0, 0, 0, 0, 0, 0, 0};
            for (int j = 0; j < deg; j += 16) {
                int e0 = j + g, e1 = j + 8 + g;
                bool p0 = e0 < deg, p1 = e1 < deg;
                int sn0 = p0 ? csr_src[start + e0] : 0;
                int sn1 = p1 ? csr_src[start + e1] : 0;
                uint4 q0 = {0, 0, 0, 0}, q1 = {0, 0, 0, 0};
                if (p0) q0 = fp4[(size_t)sn0 * 8 + l];   // 2 independent gathers
                if (p1) q1 = fp4[(size_t)sn1 * 8 + l];
                const __half2* h0 = (const __half2*)&q0;
                const __half2* h1 = (const __half2*)&q1;
                #pragma unroll
                for (int c = 0; c < 4; c++) {
                    float2 f0 = __half22float2(h0[c]);
                    float2 f1 = __half22float2(h1[c]);
                    acc[2 * c]     += f0.x + f1.x;
                    acc[2 * c + 1] += f0.y + f1.y;
                }
            }
            #pragma unroll
            for (int off = 8; off < 64; off <<= 1) {
                #pragma unroll
                for (int c = 0; c < 8; c++)
                    acc[c] += __shfl_xor(acc[c], off, 64);
            }
            float inn = rsqrtf(fmaxf((float)deg, 1.0f));
            float v2 = 0.0f;
            #pragma unroll
            for (int c = 0; c < 8; c++) {
                float h = fmaxf(inn * acc[c] + b1[l * 8 + c], 0.0f);
                v2 += h * W2[l * 8 + c];
            }
            #pragma unroll
            for (int off = 1; off < 8; off <<= 1)
                v2 += __shfl_xor(v2, off, 64);
            if (lane == 0) s_buf[n] = out_norm[n] * v2;
        }
    }
    gbar(bar, 5);

    // ---------------- P7: agg2 — 16 lanes/node + sigmoid ---------------------
    {
        int sid = (b * BS + tid) >> 4;
        int sub = lane & 15;
        for (int n = sid; n < N; n += NBLK * (BS / 16)) {
            int start = row_start[n], deg = in_deg[n];
            float a = 0.0f;
            for (int j = sub; j < deg; j += 32) {
                int j1 = j + 16;
                int i0 = csr_src[start + j];
                int i1 = (j1 < deg) ? csr_src[start + j1] : 0;
                float v0 = s_buf[i0];
                float v1 = (j1 < deg) ? s_buf[i1] : 0.0f;
                a += v0 + v1;
            }
            #pragma unroll
            for (int off = 1; off < 16; off <<= 1)
                a += __shfl_xor(a, off, 64);
            if (sub == 0) {
                float x = rsqrtf(fmaxf((float)deg, 1.0f)) * a + b2[0];
                out[n] = 1.0f / (1.0f + expf(-x));
            }
        }
    }
}

extern "C" void kernel_launch(void* const* d_in, const int* in_sizes, int n_in,
                              void* d_out, int out_size, void* d_ws, size_t ws_size,
                              hipStream_t stream) {
    const float* feat = (const float*)d_in[0];
    const float* W1   = (const float*)d_in[1];
    const float* b1   = (const float*)d_in[2];
    const float* W2   = (const float*)d_in[3];
    const float* b2   = (const float*)d_in[4];
    const int* src = (const int*)d_in[5];
    const int* dst = (const int*)d_in[6];
    float* out = (float*)d_out;

    const int N  = in_sizes[0] / 64;   // 50000
    const int E  = in_sizes[5];        // 800000
    const int NB = (N + 255) >> 8;     // 196 (must be <= 256)

    int* wsi = (int*)d_ws;
    int* bar        = wsi;                                  // NBAR*32 ints
    int* countsD    = bar + NBAR * 32;                      // NB*NBLK
    int* countsS    = countsD + (size_t)NB * NBLK;          // NB*NBLK
    int* rowSumD    = countsS + (size_t)NB * NBLK;          // NB
    int* rowSumS    = rowSumD + NB;                         // NB
    int* dstBinBase = rowSumS + NB;                         // NB+1
    int* srcBinBase = dstBinBase + NB + 1;                  // NB+1
    int* packed     = srcBinBase + NB + 1;                  // E
    int* csr_src    = packed + E;                           // E
    int* in_deg     = csr_src + E;                          // N
    int* row_start  = in_deg + N;                           // N
    unsigned char* srcPart = (unsigned char*)(row_start + N);  // E bytes
    size_t off_b = ((size_t)NBAR * 32 + 2 * (size_t)NB * NBLK + 2 * NB +
                    2 * (NB + 1) + 2 * (size_t)E + 2 * (size_t)N) * sizeof(int)
                   + (size_t)E;
    off_b = (off_b + 15) & ~(size_t)15;
    __half* featp    = (__half*)((char*)d_ws + off_b);                     // 64N
    float*  out_norm = (float*)((char*)d_ws + off_b + (size_t)64 * N * sizeof(__half));
    float*  s_buf    = out_norm + N;                        // N

    // zero only the barrier counters (monotonic targets; re-zeroed every call)
    hipMemsetAsync(bar, 0, (size_t)NBAR * 32 * sizeof(int), stream);

    gcn_persist<<<NBLK, BS, 0, stream>>>(
        feat, W1, b1, W2, b2, src, dst,
        bar, countsD, countsS, rowSumD, rowSumS, dstBinBase, srcBinBase,
        packed, srcPart, csr_src, in_deg, row_start, out_norm, s_buf,
        featp, out, N, E, NB);
}